// Round 6
// baseline (82.528 us; speedup 1.0000x reference)
//
#include <hip/hip_runtime.h>
#include <math.h>

#define NTOT 16384
#define KK 16
#define DD 16
#define NPAIR 136   // upper-tri incl diag of 16x16

// ---- ws layout (bytes) ----
#define WS_RHS   0          // float[256]     rhs_k = Sigma_k mu_k       prep->all
#define WS_WP    1024       // float[16*137]  W_k packed lower, stride137 prep->all
#define WS_LCS   9792       // float[136]     lC packed upper (+ln2)     prep->all
#define WS_ACC   10336      // u64 fixed-point accumulator (zeroed by prep)
#define WS_CNT   10344      // u64 block counter            (zeroed by prep)
#define WS_END   10352

#define LN2PI 1.8378770664093454836f
#define FXSCALE 268435456.0          // 2^28

// ---------------- K1: per-component precompute + per-pair constants ----------------
// 1 block x 1024 threads. Phase A: 16 lanes/component (256 threads).
// Phase B: 64 16-lane groups cover 136 pairs (<=3 sequential each).
__global__ __launch_bounds__(1024) void gm_prep(const float* __restrict__ mu,
                                                const float* __restrict__ L,
                                                const float* __restrict__ wts,
                                                char* __restrict__ wsb) {
  __shared__ float sSig[KK * 256];   // full Sigma rows
  __shared__ float sA[KK * 256];     // full A rows
  __shared__ float sR[256];          // rhs

  const int tid = threadIdx.x;
  if (tid == 0) {                    // zero accumulator + counter for K2
    *(unsigned long long*)(wsb + WS_ACC) = 0ULL;
    *(unsigned long long*)(wsb + WS_CNT) = 0ULL;
  }

  if (tid < 256) {
    const int k = tid >> 4;
    const int r = tid & 15;

    const float* Lk = L + k * DD * DD;
    float Lx[DD];
    #pragma unroll
    for (int b = 0; b < DD; b++) Lx[b] = (b <= r) ? Lk[r * DD + b] : 0.0f;

    // A row r = tril(L)tril(L)^T + I
    float Ar[DD];
    #pragma unroll
    for (int c = 0; c < DD; c++) {
      float s = (r == c) ? 1.0f : 0.0f;
      #pragma unroll
      for (int b = 0; b <= c; b++)
        s = fmaf(Lx[b], __shfl(Lx[b], c, 16), s);
      Ar[c] = s;
      sA[k * 256 + r * DD + c] = s;
    }

    // Cholesky A = G G^T (lane r = row r of G)
    float Gr[DD];
    #pragma unroll
    for (int m = 0; m < DD; m++) Gr[m] = 0.0f;
    #pragma unroll
    for (int c = 0; c < DD; c++) {
      float u = Ar[c];
      #pragma unroll
      for (int m = 0; m < c; m++)
        u = fmaf(-Gr[m], __shfl(Gr[m], c, 16), u);
      float d = sqrtf(__shfl(u, c, 16));
      float val = (r == c) ? d : u / d;
      if (r >= c) Gr[c] = val;
    }

    // W = G^{-1}, lane r holds COLUMN r of W
    float Wc[DD];
    #pragma unroll
    for (int m = 0; m < DD; m++) Wc[m] = 0.0f;
    #pragma unroll
    for (int rr = 0; rr < DD; rr++) {
      float s = (r == rr) ? 1.0f : 0.0f;
      #pragma unroll
      for (int m = 0; m < rr; m++)
        s = fmaf(-__shfl(Gr[m], rr, 16), Wc[m], s);
      Wc[rr] = s / __shfl(Gr[rr], rr, 16);
    }
    {
      float* Wout = (float*)(wsb + WS_WP) + k * 137;
      #pragma unroll
      for (int rr = 0; rr < DD; rr++)
        if (rr >= r) Wout[rr * (rr + 1) / 2 + r] = Wc[rr];
    }

    // Sigma row r (full) = dot(W col r, W col b)
    float Sig[DD];
    #pragma unroll
    for (int b = 0; b < DD; b++) {
      float s = 0.0f;
      #pragma unroll
      for (int rr = 0; rr < DD; rr++)
        s = fmaf(Wc[rr], __shfl(Wc[rr], b, 16), s);
      Sig[b] = s;
      sSig[k * 256 + r * DD + b] = s;
    }

    // rhs[r] = dot(Sigma row r, mu_k)
    {
      float muv = mu[k * DD + r];
      float s = 0.0f;
      #pragma unroll
      for (int b = 0; b < DD; b++)
        s = fmaf(Sig[b], __shfl(muv, b, 16), s);
      sR[k * DD + r] = s;
      ((float*)(wsb + WS_RHS))[k * DD + r] = s;
    }
  }
  __syncthreads();

  // ---------- phase B: pairs, 64 groups x <=3 sequential ----------
  const int g2 = tid >> 4;
  const int r = tid & 15;

  for (int t = 0; t < 3; t++) {
    const int p = g2 + (t << 6);
    if (p >= NPAIR) break;
    int i = 0, rem = p;
    while (rem >= (KK - i)) { rem -= (KK - i); i++; }
    const int j = i + rem;

    float Mr[DD], Gr[DD];

    // ===== Ssum = Sigma_i + Sigma_j =====
    #pragma unroll
    for (int c = 0; c < DD; c++)
      Mr[c] = sSig[i * 256 + r * DD + c] + sSig[j * 256 + r * DD + c];

    float ldS = 0.0f, mydinv = 0.0f;
    #pragma unroll
    for (int m = 0; m < DD; m++) Gr[m] = 0.0f;
    #pragma unroll
    for (int c = 0; c < DD; c++) {
      float u = Mr[c];
      #pragma unroll
      for (int m = 0; m < c; m++)
        u = fmaf(-Gr[m], __shfl(Gr[m], c, 16), u);
      float d2 = __shfl(u, c, 16);
      ldS += __logf(d2);
      float d = sqrtf(d2);
      float dinv = 1.0f / d;
      if (r == c) mydinv = dinv;
      float val = (r == c) ? d : u * dinv;
      if (r >= c) Gr[c] = val;
    }
    float cq = 0.0f;
    {
      float acc = sR[i * DD + r] + sR[j * DD + r];
      #pragma unroll
      for (int m = 0; m < DD; m++) {
        float ym = __shfl(acc, m, 16) * __shfl(mydinv, m, 16);
        cq = fmaf(ym, ym, cq);
        if (r > m) acc = fmaf(-Gr[m], ym, acc);
      }
    }

    // ===== Asum = A_i + A_j =====
    #pragma unroll
    for (int c = 0; c < DD; c++)
      Mr[c] = sA[i * 256 + r * DD + c] + sA[j * 256 + r * DD + c];

    float ldA = 0.0f, mydinvA = 0.0f;
    #pragma unroll
    for (int m = 0; m < DD; m++) Gr[m] = 0.0f;
    #pragma unroll
    for (int c = 0; c < DD; c++) {
      float u = Mr[c];
      #pragma unroll
      for (int m = 0; m < c; m++)
        u = fmaf(-Gr[m], __shfl(Gr[m], c, 16), u);
      float d2 = __shfl(u, c, 16);
      ldA += __logf(d2);
      float d = sqrtf(d2);
      float dinv = 1.0f / d;
      if (r == c) mydinvA = dinv;
      float val = (r == c) ? d : u * dinv;
      if (r >= c) Gr[c] = val;
    }
    float q = 0.0f;
    {
      float acc = mu[i * DD + r] - mu[j * DD + r];
      #pragma unroll
      for (int m = 0; m < DD; m++) {
        float ym = __shfl(acc, m, 16) * __shfl(mydinvA, m, 16);
        q = fmaf(ym, ym, q);
        if (r > m) acc = fmaf(-Gr[m], ym, acc);
      }
    }

    if (r == 0) {
      float lC = -0.5f * q - 0.5f * ldA + 0.5f * ldS - (float)DD * LN2PI
                 + __logf(wts[i]) + __logf(wts[j]) - 0.5f * cq;
      if (i < j) lC += 0.69314718056f;
      ((float*)(wsb + WS_LCS))[p] = lC;
    }
  }
}

// ---------------- K2: per-sample log pdf + in-kernel finalize ----------------
// 512 blocks x 256 threads; each block handles 2 tiles of 16 samples.
__global__ __launch_bounds__(256) void gm_all(const float* __restrict__ X,
                                              char* __restrict__ wsb,
                                              float* __restrict__ out) {
  __shared__ float sW[KK * 137];
  __shared__ float sR[KK * 17];
  __shared__ float sLC[NPAIR];
  __shared__ unsigned char sIJ[NPAIR];
  __shared__ float sX[256];
  __shared__ float sE[16 * 17];
  __shared__ double sD[16];

  const int tid = threadIdx.x;
  const int s = tid >> 4;
  const int r = tid & 15;

  // ---- stage constants once ----
  {
    const float* Wp = (const float*)(wsb + WS_WP);
    for (int idx = tid; idx < KK * 137; idx += 256) sW[idx] = Wp[idx];
    const float* Rf = (const float*)(wsb + WS_RHS);
    sR[s * 17 + r] = Rf[tid];
    const float* lc = (const float*)(wsb + WS_LCS);
    if (tid < NPAIR) {
      sLC[tid] = lc[tid];
      int i = 0, rem = tid;
      while (rem >= (KK - i)) { rem -= (KK - i); i++; }
      sIJ[tid] = (unsigned char)((i << 4) | (i + rem));
    }
  }

  double blockAcc = 0.0;

  #pragma unroll
  for (int tile = 0; tile < 2; tile++) {
    __syncthreads();   // constants staged / previous tile's sX,sE consumed
    if (tid < 64)
      ((float4*)sX)[tid] =
        ((const float4*)(X + ((size_t)blockIdx.x * 2 + tile) * 256))[tid];
    __syncthreads();

    float x[DD];
    {
      float4 b0 = ((const float4*)sX)[s * 4 + 0];
      float4 b1 = ((const float4*)sX)[s * 4 + 1];
      float4 b2 = ((const float4*)sX)[s * 4 + 2];
      float4 b3 = ((const float4*)sX)[s * 4 + 3];
      x[0]=b0.x; x[1]=b0.y; x[2]=b0.z; x[3]=b0.w;
      x[4]=b1.x; x[5]=b1.y; x[6]=b1.z; x[7]=b1.w;
      x[8]=b2.x; x[9]=b2.y; x[10]=b2.z; x[11]=b2.w;
      x[12]=b3.x; x[13]=b3.y; x[14]=b3.z; x[15]=b3.w;
    }

    // e_r = h - g/2 for component r
    {
      const float* Wk = &sW[r * 137];
      float g = 0.0f;
      #pragma unroll
      for (int rr = 0; rr < DD; rr++) {
        float y = 0.0f;
        #pragma unroll
        for (int c = 0; c <= rr; c++) y = fmaf(Wk[rr * (rr + 1) / 2 + c], x[c], y);
        g = fmaf(y, y, g);
      }
      float h = 0.0f;
      #pragma unroll
      for (int d = 0; d < DD; d++) h = fmaf(sR[r * 17 + d], x[d], h);
      sE[s * 17 + r] = fmaf(-0.5f, g, h);
    }
    __syncthreads();

    // pairs: 8-9 per lane; two-pass log-sum-exp, width-16 reductions
    float val[9];
    float T = -3.0e38f;
    #pragma unroll
    for (int t = 0; t < 9; t++) {
      int p = t * 16 + r;
      if (t < 8 || r < 8) {
        int ij = sIJ[p];
        val[t] = sLC[p] + sE[s * 17 + (ij >> 4)] + sE[s * 17 + (ij & 15)];
      } else {
        val[t] = -3.0e38f;
      }
      T = fmaxf(T, val[t]);
    }
    #pragma unroll
    for (int w = 1; w < 16; w <<= 1) T = fmaxf(T, __shfl_xor(T, w, 16));

    float sum = 0.0f;
    #pragma unroll
    for (int t = 0; t < 9; t++) sum += __expf(val[t] - T);
    #pragma unroll
    for (int w = 1; w < 16; w <<= 1) sum += __shfl_xor(sum, w, 16);

    if (r == 0) sD[s] = (double)(T + __logf(sum));
    __syncthreads();
    if (tid == 0) {
      double acc = 0.0;
      #pragma unroll
      for (int m = 0; m < 16; m++) acc += sD[m];
      blockAcc += acc;
    }
  }

  // ---- finalize: fixed-point atomic accumulate + last-block writeout ----
  if (tid == 0) {
    double scaled = blockAcc * FXSCALE;
    long long fx = (long long)(scaled + (scaled >= 0.0 ? 0.5 : -0.5));
    unsigned long long* acc = (unsigned long long*)(wsb + WS_ACC);
    unsigned long long* cnt = (unsigned long long*)(wsb + WS_CNT);
    atomicAdd(acc, (unsigned long long)fx);
    __threadfence();
    unsigned long long old = atomicAdd(cnt, 1ULL);
    if (old == (unsigned long long)(gridDim.x - 1)) {
      __threadfence();
      unsigned long long tot = atomicAdd(acc, 0ULL);
      out[0] = (float)((double)(long long)tot * (1.0 / FXSCALE) * (1.0 / 16384.0));
    }
  }
}

extern "C" void kernel_launch(void* const* d_in, const int* in_sizes, int n_in,
                              void* d_out, int out_size, void* d_ws, size_t ws_size,
                              hipStream_t stream) {
  const float* X   = (const float*)d_in[0];
  const float* mu  = (const float*)d_in[1];
  const float* L   = (const float*)d_in[2];
  const float* wts = (const float*)d_in[3];
  char* wsb = (char*)d_ws;
  if (ws_size < WS_END) return;

  hipLaunchKernelGGL(gm_prep, dim3(1), dim3(1024), 0, stream, mu, L, wts, wsb);
  hipLaunchKernelGGL(gm_all,  dim3(NTOT / 32), dim3(256), 0, stream, X, wsb,
                     (float*)d_out);
}